// Round 14
// baseline (54.568 us; speedup 1.0000x reference)
//
#include <hip/hip_runtime.h>
#include <hip/hip_fp16.h>

typedef _Float16 half8 __attribute__((ext_vector_type(8)));
typedef _Float16 half4v __attribute__((ext_vector_type(4)));
typedef float float4v __attribute__((ext_vector_type(4)));

#define E_DIM 300
#define KP 320               // padded K (10 MFMA k-steps of 32)
#define B_ 32
#define NROW_CDD 3200        // 32*5*20
#define NROW_HIS 32000       // 32*50*20

// ---------------- Kernel 1: gather + l2-normalize -> fp16 rows (K padded to 320) --------
__global__ __launch_bounds__(256) void gather_norm(const int* __restrict__ cand,
                                                   const int* __restrict__ clk,
                                                   const float* __restrict__ emb,
                                                   _Float16* __restrict__ outH)
{
    int row  = blockIdx.x * 4 + (threadIdx.x >> 6);
    int lane = threadIdx.x & 63;
    int tok = (row < NROW_CDD) ? cand[row] : clk[row - NROW_CDD];
    const float* e = emb + (long)tok * E_DIM;
    float v[5];
    float ss = 0.f;
#pragma unroll
    for (int j = 0; j < 5; ++j) {
        int idx = lane + j * 64;
        float x = (idx < E_DIM) ? e[idx] : 0.f;
        v[j] = x;
        ss += x * x;
    }
#pragma unroll
    for (int off = 32; off; off >>= 1) ss += __shfl_xor(ss, off);
    float scale = 1.0f / fmaxf(sqrtf(ss), 1e-12f);
    _Float16* o = outH + (long)row * KP;
#pragma unroll
    for (int j = 0; j < 5; ++j) {
        int idx = lane + j * 64;
        o[idx] = (_Float16)((idx < E_DIM) ? v[j] * scale : 0.f);
    }
}

// ---------------- Kernel 2: staged sim GEMM, 2 blocks/CU, ~4 rounds (overlap) ----------
// grid (63, 32) = 2016 blocks, 256 threads (4 waves). Tile: all 100 A rows x 16 B cols.
// LDS: A 64000 + B 10240 + fp16 simT 3616 = 77.9 KB -> 2 blocks/CU.
// B read once globally (20.5 MB); A re-reads L2-hot. Two-phase hoisted staging + XOR swizzle.
__global__ __launch_bounds__(256, 2) void sim_gemm(const _Float16* __restrict__ wsH,
                                                   _Float16* __restrict__ simW)
{
    __shared__ __align__(16) char Abuf[100 * 640];       // 64000 B (linear rows + XOR)
    __shared__ __align__(16) char Bbuf[16 * 640];        // 10240 B
    __shared__ _Float16 simT[100 * 18];                  // 3600 B, stride 18
    int b = blockIdx.y, ntile = blockIdx.x;              // ntile 0..62 -> cols 16*ntile..+15
    int tid = threadIdx.x;
    int wave = tid >> 6, lane = tid & 63;
    int g = lane >> 4, r16 = lane & 15;

    const char* gA = (const char*)(wsH + (size_t)b * 100 * KP);
    const char* gB = (const char*)(wsH + (size_t)(NROW_CDD + b * 1000 + ntile * 16) * KP);
    int nclamp = (ntile == 62) ? 8 : 16;                 // cols 992..999 for last tile

    // ---- phase 1: hoist ALL independent global loads ----
    uint4 av[16], bv[3];
#pragma unroll
    for (int j = 0; j < 16; ++j) {
        int u = tid + 256 * j; if (u > 3999) u = 3999;
        av[j] = *(const uint4*)(gA + (size_t)u * 16);
    }
#pragma unroll
    for (int j = 0; j < 3; ++j) {
        int u = tid + 256 * j;                            // 640 total of 16 rows
        int uu = u; if (uu > 639) uu = 639;
        int r = uu / 40;
        int rc = (r >= nclamp) ? (nclamp - 1) : r;        // clamp pad rows inside b
        bv[j] = *(const uint4*)(gB + (size_t)(rc * 40 + (uu - r * 40)) * 16);
    }

    // ---- phase 2: LDS writes, swizzled byte ^ ((row&7)<<4) ----
#pragma unroll
    for (int j = 0; j < 16; ++j) {
        int u = tid + 256 * j;
        if (u < 4000) {
            int r = u / 40;
            *(uint4*)(Abuf + ((u * 16) ^ ((r & 7) << 4))) = av[j];
        }
    }
#pragma unroll
    for (int j = 0; j < 3; ++j) {
        int u = tid + 256 * j;
        if (u < 640) {
            int r = u / 40;
            *(uint4*)(Bbuf + ((u * 16) ^ ((r & 7) << 4))) = bv[j];
        }
    }
    __syncthreads();

    // ---- MFMA: wave w covers m = w and w+4 (wave 3: m=3 only for second slot clamp) ----
    float4v acc[2];
    acc[0] = (float4v){0.f, 0.f, 0.f, 0.f};
    acc[1] = (float4v){0.f, 0.f, 0.f, 0.f};
    int m0 = wave, m1 = (wave + 4 < 7) ? (wave + 4) : 6;  // m1 dup for wave 3 (discard)

#pragma unroll
    for (int k = 0; k < 10; ++k) {
        int rB = r16;                                     // 16 rows
        half8 bf = *(const half8*)(Bbuf + ((rB * 640 + k * 64 + g * 16) ^ ((rB & 7) << 4)));
        int rA0 = m0 * 16 + r16; if (rA0 > 99) rA0 = 99;
        int rA1 = m1 * 16 + r16; if (rA1 > 99) rA1 = 99;
        half8 af0 = *(const half8*)(Abuf + ((rA0 * 640 + k * 64 + g * 16) ^ ((rA0 & 7) << 4)));
        half8 af1 = *(const half8*)(Abuf + ((rA1 * 640 + k * 64 + g * 16) ^ ((rA1 & 7) << 4)));
        acc[0] = __builtin_amdgcn_mfma_f32_16x16x32_f16(af0, bf, acc[0], 0, 0, 0);
        acc[1] = __builtin_amdgcn_mfma_f32_16x16x32_f16(af1, bf, acc[1], 0, 0, 0);
    }

    // C/D layout (validated r1-r13): col = lane&15 (B-row), row = (lane>>4)*4+j (A-row)
#pragma unroll
    for (int mi = 0; mi < 2; ++mi) {
        int m = mi ? m1 : m0;
        if (mi == 0 || wave < 3) {
#pragma unroll
            for (int j = 0; j < 4; ++j) {
                int r = m * 16 + g * 4 + j;
                if (r < 100) simT[r * 18 + r16] = (_Float16)acc[mi][j];
            }
        }
    }
    __syncthreads();

    // coalesced-ish fp16 write-out: 100 rows x nclamp cols
    size_t obase = (size_t)b * 100000 + (size_t)ntile * 16;
    for (int u = tid; u < 100 * 16; u += 256) {
        int r = u >> 4, c = u & 15;
        if (c < nclamp) simW[obase + (size_t)r * 1000 + c] = simT[r * 18 + c];
    }
}

// ---------------- Kernel 3: gaussian kernels + log pooling, one block per sim row -------
__global__ __launch_bounds__(256) void knrm_pool(const _Float16* __restrict__ simW,
                                                 const float* __restrict__ cpad,
                                                 const float* __restrict__ hpad,
                                                 const float* __restrict__ ltr_w,
                                                 float* __restrict__ rowsum)
{
    __shared__ float sS[50 * 21];
    __shared__ float mS[50 * 21];
    __shared__ float wS[1000];
    __shared__ float part[4];

    int row = blockIdx.x;            // (b*5+c)*20 + s
    int b = row / 100;
    int tid = threadIdx.x;

    if (tid < 250) {
        int p = tid * 4;
        half4v hv = *(const half4v*)(simW + (size_t)row * 1000 + p);
        float4v mv = *(const float4v*)(hpad + (size_t)b * 1000 + p);
        *(float4v*)&wS[p] = *(const float4v*)(ltr_w + p);
#pragma unroll
        for (int q = 0; q < 4; ++q) {
            int pq = p + q, h = pq / 20, t = pq - h * 20;
            sS[h * 21 + t] = (float)hv[q];
            mS[h * 21 + t] = mv[q];
        }
    }
    __syncthreads();

    float val = 0.f;
    if (tid < 250) {
        int h = tid % 50, kq = tid / 50;     // kq 0..4, k = kq*4+j
        float bj[4], cj[4];
        bool is19[4];
#pragma unroll
        for (int j = 0; j < 4; ++j) {
            float mu = -0.9f + 0.1f * (float)(kq * 4 + j);
            bj[j] = 100.0f * mu;
            cj[j] = -50.0f * mu * mu;
            is19[j] = (kq * 4 + j) == 19;
        }
        float psum0 = 0.f, psum1 = 0.f, psum2 = 0.f, psum3 = 0.f;
        const float* sp = sS + h * 21;
        const float* mp = mS + h * 21;
#pragma unroll 4
        for (int t = 0; t < 20; ++t) {
            float s  = sp[t];
            float mm = mp[t];
            float d  = s - 1.0f;
            float arg19 = -500000.0f * d * d;
            float a0 = is19[0] ? arg19 : fmaf(fmaf(-50.0f, s, bj[0]), s, cj[0]);
            float a1 = is19[1] ? arg19 : fmaf(fmaf(-50.0f, s, bj[1]), s, cj[1]);
            float a2 = is19[2] ? arg19 : fmaf(fmaf(-50.0f, s, bj[2]), s, cj[2]);
            float a3 = is19[3] ? arg19 : fmaf(fmaf(-50.0f, s, bj[3]), s, cj[3]);
            psum0 = fmaf(__expf(a0), mm, psum0);
            psum1 = fmaf(__expf(a1), mm, psum1);
            psum2 = fmaf(__expf(a2), mm, psum2);
            psum3 = fmaf(__expf(a3), mm, psum3);
        }
        const float* wp = wS + h * 20 + kq * 4;
        val  = __logf(fmaxf(psum0, 1e-10f)) * wp[0];
        val += __logf(fmaxf(psum1, 1e-10f)) * wp[1];
        val += __logf(fmaxf(psum2, 1e-10f)) * wp[2];
        val += __logf(fmaxf(psum3, 1e-10f)) * wp[3];
    }
#pragma unroll
    for (int off = 32; off; off >>= 1) val += __shfl_down(val, off);
    int wave = tid >> 6, lane = tid & 63;
    if (lane == 0) part[wave] = val;
    __syncthreads();
    if (tid == 0)
        rowsum[row] = (part[0] + part[1] + part[2] + part[3]) * 0.01f * cpad[row];
}

// ---------------- Kernel 4: sum rows per (b,c) + bias + log_softmax over C=5 ------------
__global__ __launch_bounds__(64) void finalize(const float* __restrict__ rowsum,
                                               const float* __restrict__ ltr_b,
                                               float* __restrict__ out)
{
    int b = blockIdx.x;
    int tid = threadIdx.x;
    __shared__ float sc[5];
    if (tid < 5) {
        float a = ltr_b[0];
        const float* rp = rowsum + (b * 5 + tid) * 20;
#pragma unroll
        for (int s = 0; s < 20; ++s) a += rp[s];
        sc[tid] = a;
    }
    __syncthreads();
    if (tid < 5) {
        float m = fmaxf(fmaxf(fmaxf(sc[0], sc[1]), fmaxf(sc[2], sc[3])), sc[4]);
        float sum = 0.f;
#pragma unroll
        for (int i = 0; i < 5; ++i) sum += __expf(sc[i] - m);
        out[b * 5 + tid] = sc[tid] - m - __logf(sum);
    }
}

extern "C" void kernel_launch(void* const* d_in, const int* in_sizes, int n_in,
                              void* d_out, int out_size, void* d_ws, size_t ws_size,
                              hipStream_t stream)
{
    const int*   cand = (const int*)d_in[0];
    const int*   clk  = (const int*)d_in[1];
    const float* cpad = (const float*)d_in[2];
    const float* hpad = (const float*)d_in[3];
    const float* emb  = (const float*)d_in[4];
    const float* lw   = (const float*)d_in[5];
    const float* lb   = (const float*)d_in[6];
    float* out = (float*)d_out;

    _Float16* wsH  = (_Float16*)d_ws;                                                   // 22.528 MB
    _Float16* simW = (_Float16*)((char*)d_ws + (size_t)(NROW_CDD + NROW_HIS) * KP * 2); // 6.4 MB
    float* rowsum  = (float*)((char*)simW + (size_t)B_ * 100 * 1000 * 2);               // 12.8 KB

    hipLaunchKernelGGL(gather_norm, dim3((NROW_CDD + NROW_HIS) / 4), dim3(256), 0, stream,
                       cand, clk, emb, wsH);
    hipLaunchKernelGGL(sim_gemm, dim3(63, B_), dim3(256), 0, stream, wsH, simW);
    hipLaunchKernelGGL(knrm_pool, dim3(NROW_CDD), dim3(256), 0, stream,
                       simW, cpad, hpad, lw, rowsum);
    hipLaunchKernelGGL(finalize, dim3(B_), dim3(64), 0, stream, rowsum, lb, out);
}

// Round 15
// 53.830 us; speedup vs baseline: 1.0137x; 1.0137x over previous
//
#include <hip/hip_runtime.h>
#include <hip/hip_fp16.h>

typedef _Float16 half8 __attribute__((ext_vector_type(8)));
typedef _Float16 half4v __attribute__((ext_vector_type(4)));
typedef float float4v __attribute__((ext_vector_type(4)));

#define E_DIM 300
#define KP 320               // padded K (10 MFMA k-steps of 32)
#define B_ 32
#define NROW_CDD 3200        // 32*5*20
#define NROW_HIS 32000       // 32*50*20

// ---------------- Kernel 1: gather + l2-normalize, XCD-swizzled by batch ----------------
// grid 8800 (= 8 xcd x 1100), 256 threads = 4 rows. All rows of batch b on XCD b%8.
__global__ __launch_bounds__(256) void gather_norm(const int* __restrict__ cand,
                                                   const int* __restrict__ clk,
                                                   const float* __restrict__ emb,
                                                   _Float16* __restrict__ outH)
{
    int g = blockIdx.x;
    int xcd = g & 7;
    int i = g >> 3;                      // 0..1099
    int bq = i / 275;                    // 0..3
    int local = i - bq * 275;            // 0..274
    int b = xcd + 8 * bq;                // 0..31
    int lr = local * 4 + (threadIdx.x >> 6);   // 0..1099: row within b (100 cdd + 1000 his)
    int lane = threadIdx.x & 63;

    int tok, orow;
    if (lr < 100) { tok = cand[b * 100 + lr];          orow = b * 100 + lr; }
    else          { tok = clk[b * 1000 + (lr - 100)];  orow = NROW_CDD + b * 1000 + (lr - 100); }

    const float* e = emb + (size_t)tok * E_DIM;
    float v[5];
    float ss = 0.f;
#pragma unroll
    for (int j = 0; j < 5; ++j) {
        int idx = lane + j * 64;
        float x = (idx < E_DIM) ? e[idx] : 0.f;
        v[j] = x;
        ss += x * x;
    }
#pragma unroll
    for (int off = 32; off; off >>= 1) ss += __shfl_xor(ss, off);
    float scale = 1.0f / fmaxf(sqrtf(ss), 1e-12f);
    _Float16* o = outH + (size_t)orow * KP;
#pragma unroll
    for (int j = 0; j < 5; ++j) {
        int idx = lane + j * 64;
        o[idx] = (_Float16)((idx < E_DIM) ? v[j] * scale : 0.f);
    }
}

// ---------------- Kernel 2: streaming 32x32 wave-tile GEMM, XCD-local L2 ----------------
// grid 1024 (= 8 xcd x 128), 256 threads (4 waves). No LDS, no barriers.
// Per wave: 32x32 tile, per k: 4 indep 16B loads + 4 MFMAs. 168 MB total, L2-resident/XCD.
__global__ __launch_bounds__(256, 4) void sim_gemm(const _Float16* __restrict__ wsH,
                                                   _Float16* __restrict__ simW)
{
    int g = blockIdx.x;
    int xcd = g & 7;
    int i = g >> 3;                  // 0..127
    int b = xcd + 8 * (i >> 5);      // 0..31 (same-b blocks share an XCD)
    int tg = i & 31;
    int tid = threadIdx.x;
    int wave = tid >> 6, lane = tid & 63;
    int g4 = lane >> 4, r16 = lane & 15;

    int tile = tg * 4 + wave;        // 0..127
    int m = tile >> 5;               // 0..3  (rows m*32..+31, clamped at 100)
    int n = tile & 31;               // 0..31 (cols n*32..+31, clamped at 1000)

    const char* gA = (const char*)(wsH + (size_t)b * 100 * KP);
    const char* gB = (const char*)(wsH + (size_t)(NROW_CDD + b * 1000) * KP);

    const char* pA[2];
    const char* pB[2];
#pragma unroll
    for (int q = 0; q < 2; ++q) {
        int rA = m * 32 + q * 16 + r16; if (rA > 99) rA = 99;
        pA[q] = gA + (size_t)rA * 640;
        int rB = n * 32 + q * 16 + r16; if (rB > 999) rB = 999;
        pB[q] = gB + (size_t)rB * 640;
    }

    float4v acc[2][2];
#pragma unroll
    for (int mm = 0; mm < 2; ++mm)
#pragma unroll
        for (int nn = 0; nn < 2; ++nn) acc[mm][nn] = (float4v){0.f, 0.f, 0.f, 0.f};

#pragma unroll
    for (int k = 0; k < 10; ++k) {
        half8 af0 = *(const half8*)(pA[0] + k * 64 + g4 * 16);
        half8 af1 = *(const half8*)(pA[1] + k * 64 + g4 * 16);
        half8 bf0 = *(const half8*)(pB[0] + k * 64 + g4 * 16);
        half8 bf1 = *(const half8*)(pB[1] + k * 64 + g4 * 16);
        acc[0][0] = __builtin_amdgcn_mfma_f32_16x16x32_f16(af0, bf0, acc[0][0], 0, 0, 0);
        acc[0][1] = __builtin_amdgcn_mfma_f32_16x16x32_f16(af0, bf1, acc[0][1], 0, 0, 0);
        acc[1][0] = __builtin_amdgcn_mfma_f32_16x16x32_f16(af1, bf0, acc[1][0], 0, 0, 0);
        acc[1][1] = __builtin_amdgcn_mfma_f32_16x16x32_f16(af1, bf1, acc[1][1], 0, 0, 0);
    }

    // C/D layout (validated r1-r14): col = lane&15 (B-row), row = (lane>>4)*4+j (A-row)
    size_t obase = (size_t)b * 100000;
#pragma unroll
    for (int mm = 0; mm < 2; ++mm) {
#pragma unroll
        for (int nn = 0; nn < 2; ++nn) {
            int col = n * 32 + nn * 16 + r16;
            if (col < 1000) {
#pragma unroll
                for (int j = 0; j < 4; ++j) {
                    int r = m * 32 + mm * 16 + g4 * 4 + j;
                    if (r < 100) simW[obase + (size_t)r * 1000 + col] = (_Float16)acc[mm][nn][j];
                }
            }
        }
    }
}

// ---------------- Kernel 3: gaussian kernels + log pooling, XCD-swizzled ----------------
// grid 3200 (= 8 xcd x 400), 256 threads (250 active). simW rows L2-local to their XCD.
__global__ __launch_bounds__(256) void knrm_pool(const _Float16* __restrict__ simW,
                                                 const float* __restrict__ cpad,
                                                 const float* __restrict__ hpad,
                                                 const float* __restrict__ ltr_w,
                                                 float* __restrict__ rowsum)
{
    __shared__ float sS[50 * 21];
    __shared__ float mS[50 * 21];
    __shared__ float wS[1000];
    __shared__ float part[4];

    int g = blockIdx.x;
    int i = g >> 3;                          // 0..399
    int b = (g & 7) + 8 * (i / 100);         // 0..31
    int row = b * 100 + (i % 100);           // (b*5+c)*20 + s
    int tid = threadIdx.x;

    if (tid < 250) {
        int p = tid * 4;
        half4v hv = *(const half4v*)(simW + (size_t)row * 1000 + p);
        float4v mv = *(const float4v*)(hpad + (size_t)b * 1000 + p);
        *(float4v*)&wS[p] = *(const float4v*)(ltr_w + p);
#pragma unroll
        for (int q = 0; q < 4; ++q) {
            int pq = p + q, h = pq / 20, t = pq - h * 20;
            sS[h * 21 + t] = (float)hv[q];
            mS[h * 21 + t] = mv[q];
        }
    }
    __syncthreads();

    float val = 0.f;
    if (tid < 250) {
        int h = tid % 50, kq = tid / 50;     // kq 0..4, k = kq*4+j
        float bj[4], cj[4];
        bool is19[4];
#pragma unroll
        for (int j = 0; j < 4; ++j) {
            float mu = -0.9f + 0.1f * (float)(kq * 4 + j);
            bj[j] = 100.0f * mu;
            cj[j] = -50.0f * mu * mu;
            is19[j] = (kq * 4 + j) == 19;
        }
        float psum0 = 0.f, psum1 = 0.f, psum2 = 0.f, psum3 = 0.f;
        const float* sp = sS + h * 21;
        const float* mp = mS + h * 21;
#pragma unroll 4
        for (int t = 0; t < 20; ++t) {
            float s  = sp[t];
            float mm = mp[t];
            float d  = s - 1.0f;
            float arg19 = -500000.0f * d * d;
            float a0 = is19[0] ? arg19 : fmaf(fmaf(-50.0f, s, bj[0]), s, cj[0]);
            float a1 = is19[1] ? arg19 : fmaf(fmaf(-50.0f, s, bj[1]), s, cj[1]);
            float a2 = is19[2] ? arg19 : fmaf(fmaf(-50.0f, s, bj[2]), s, cj[2]);
            float a3 = is19[3] ? arg19 : fmaf(fmaf(-50.0f, s, bj[3]), s, cj[3]);
            psum0 = fmaf(__expf(a0), mm, psum0);
            psum1 = fmaf(__expf(a1), mm, psum1);
            psum2 = fmaf(__expf(a2), mm, psum2);
            psum3 = fmaf(__expf(a3), mm, psum3);
        }
        const float* wp = wS + h * 20 + kq * 4;
        val  = __logf(fmaxf(psum0, 1e-10f)) * wp[0];
        val += __logf(fmaxf(psum1, 1e-10f)) * wp[1];
        val += __logf(fmaxf(psum2, 1e-10f)) * wp[2];
        val += __logf(fmaxf(psum3, 1e-10f)) * wp[3];
    }
#pragma unroll
    for (int off = 32; off; off >>= 1) val += __shfl_down(val, off);
    int wave = tid >> 6, lane = tid & 63;
    if (lane == 0) part[wave] = val;
    __syncthreads();
    if (tid == 0)
        rowsum[row] = (part[0] + part[1] + part[2] + part[3]) * 0.01f * cpad[row];
}

// ---------------- Kernel 4: sum rows per (b,c) + bias + log_softmax over C=5 ------------
__global__ __launch_bounds__(64) void finalize(const float* __restrict__ rowsum,
                                               const float* __restrict__ ltr_b,
                                               float* __restrict__ out)
{
    int b = blockIdx.x;
    int tid = threadIdx.x;
    __shared__ float sc[5];
    if (tid < 5) {
        float a = ltr_b[0];
        const float* rp = rowsum + (b * 5 + tid) * 20;
#pragma unroll
        for (int s = 0; s < 20; ++s) a += rp[s];
        sc[tid] = a;
    }
    __syncthreads();
    if (tid < 5) {
        float m = fmaxf(fmaxf(fmaxf(sc[0], sc[1]), fmaxf(sc[2], sc[3])), sc[4]);
        float sum = 0.f;
#pragma unroll
        for (int i = 0; i < 5; ++i) sum += __expf(sc[i] - m);
        out[b * 5 + tid] = sc[tid] - m - __logf(sum);
    }
}

extern "C" void kernel_launch(void* const* d_in, const int* in_sizes, int n_in,
                              void* d_out, int out_size, void* d_ws, size_t ws_size,
                              hipStream_t stream)
{
    const int*   cand = (const int*)d_in[0];
    const int*   clk  = (const int*)d_in[1];
    const float* cpad = (const float*)d_in[2];
    const float* hpad = (const float*)d_in[3];
    const float* emb  = (const float*)d_in[4];
    const float* lw   = (const float*)d_in[5];
    const float* lb   = (const float*)d_in[6];
    float* out = (float*)d_out;

    _Float16* wsH  = (_Float16*)d_ws;                                                   // 22.528 MB
    _Float16* simW = (_Float16*)((char*)d_ws + (size_t)(NROW_CDD + NROW_HIS) * KP * 2); // 6.4 MB
    float* rowsum  = (float*)((char*)simW + (size_t)B_ * 100 * 1000 * 2);               // 12.8 KB

    hipLaunchKernelGGL(gather_norm, dim3(8800), dim3(256), 0, stream, cand, clk, emb, wsH);
    hipLaunchKernelGGL(sim_gemm, dim3(1024), dim3(256), 0, stream, wsH, simW);
    hipLaunchKernelGGL(knrm_pool, dim3(3200), dim3(256), 0, stream,
                       simW, cpad, hpad, lw, rowsum);
    hipLaunchKernelGGL(finalize, dim3(B_), dim3(64), 0, stream, rowsum, lb, out);
}

// Round 16
// 52.774 us; speedup vs baseline: 1.0340x; 1.0200x over previous
//
#include <hip/hip_runtime.h>
#include <hip/hip_fp16.h>

typedef _Float16 half8 __attribute__((ext_vector_type(8)));
typedef float float4v __attribute__((ext_vector_type(4)));

#define E_DIM 300
#define KP 320               // padded K (10 MFMA k-steps of 32)
#define B_ 32
#define NROW_CDD 3200        // 32*5*20
#define NROW_HIS 32000       // 32*50*20
#define NCHUNK 10            // 5 h per chunk, 100 his rows

typedef const void __attribute__((address_space(1))) gvoid;
typedef void __attribute__((address_space(3))) lvoid;
__device__ __forceinline__ void gload16(const void* g, void* l) {
    __builtin_amdgcn_global_load_lds((gvoid*)g, (lvoid*)l, 16, 0, 0);
}

// ---------------- Kernel 1: gather + l2-normalize -> fp16 rows (K padded to 320) --------
__global__ __launch_bounds__(256) void gather_norm(const int* __restrict__ cand,
                                                   const int* __restrict__ clk,
                                                   const float* __restrict__ emb,
                                                   _Float16* __restrict__ outH)
{
    int row  = blockIdx.x * 4 + (threadIdx.x >> 6);
    int lane = threadIdx.x & 63;
    int tok = (row < NROW_CDD) ? cand[row] : clk[row - NROW_CDD];
    const float* e = emb + (long)tok * E_DIM;
    float v[5];
    float ss = 0.f;
#pragma unroll
    for (int j = 0; j < 5; ++j) {
        int idx = lane + j * 64;
        float x = (idx < E_DIM) ? e[idx] : 0.f;
        v[j] = x;
        ss += x * x;
    }
#pragma unroll
    for (int off = 32; off; off >>= 1) ss += __shfl_xor(ss, off);
    float scale = 1.0f / fmaxf(sqrtf(ss), 1e-12f);
    _Float16* o = outH + (long)row * KP;
#pragma unroll
    for (int j = 0; j < 5; ++j) {
        int idx = lane + j * 64;
        o[idx] = (_Float16)((idx < E_DIM) ? v[j] * scale : 0.f);
    }
}

// ---------------- Kernel 2: fused GEMM + pooling, async global_load_lds staging ---------
// grid (10, 32) = 320 blocks, 512 threads. LDS ~155 KB -> 1 block/CU.
// Stage A(100x640) + B-chunk(100x640) via global_load_lds w=16 (linear LDS dest,
// pre-swizzled per-lane SOURCE addr: src = off ^ ((row&7)<<4), involution cancels on read).
__global__ __launch_bounds__(512, 1) void knrm_fused(const _Float16* __restrict__ wsH,
                                                     const float* __restrict__ cpad,
                                                     const float* __restrict__ hpad,
                                                     const float* __restrict__ ltr_w,
                                                     float* __restrict__ partial)
{
    __shared__ __align__(16) char Abuf[65536];
    __shared__ __align__(16) char Bbuf[65536];
    __shared__ _Float16 simL[100 * 102];     // 20400 B, fp16, stride 102
    __shared__ float mS[100];
    __shared__ float wS[100];
    __shared__ float cS[100];
    __shared__ float svals[500];

    int b = blockIdx.y, chunk = blockIdx.x;
    int tid = threadIdx.x;
    int wave = tid >> 6, lane = tid & 63;
    int g4 = lane >> 4, r16 = lane & 15;

    const char* gA = (const char*)(wsH + (size_t)b * 100 * KP);
    const char* gB = (const char*)(wsH + (size_t)(NROW_CDD + b * 1000 + chunk * 100) * KP);

    // ---- async stage: per wave 8 KB of A + 8 KB of B (16 calls, all in flight) ----
#pragma unroll
    for (int c = 0; c < 8; ++c) {
        int lds_off = wave * 8192 + c * 1024;
        int my = lds_off + lane * 16;
        int r = my / 640;
        int src = my ^ ((r & 7) << 4);       // stays within the 640-B row (col*16<=624+112<640? col<40 -> ok)
        gload16(gA + src, Abuf + lds_off);
        gload16(gB + src, Bbuf + lds_off);
    }
    if (tid < 100) {
        mS[tid] = hpad[b * 1000 + chunk * 100 + tid];
        wS[tid] = ltr_w[chunk * 100 + tid];
        cS[tid] = cpad[b * 100 + tid];
    }
    __syncthreads();   // drains vmcnt(0) incl. global_load_lds

    // ---- MFMA: 100x100 sim tile, wave w = m-tile w (7 active waves) ----
    if (wave < 7) {
        float4v acc[7];
#pragma unroll
        for (int n = 0; n < 7; ++n) acc[n] = (float4v){0.f, 0.f, 0.f, 0.f};
        int rA = wave * 16 + r16; if (rA > 99) rA = 99;
#pragma unroll
        for (int k = 0; k < 10; ++k) {
            half8 af = *(const half8*)(Abuf + ((rA * 640 + k * 64 + g4 * 16) ^ ((rA & 7) << 4)));
#pragma unroll
            for (int n = 0; n < 7; ++n) {
                int rB = n * 16 + r16; if (rB > 99) rB = 99;
                half8 bf = *(const half8*)(Bbuf + ((rB * 640 + k * 64 + g4 * 16) ^ ((rB & 7) << 4)));
                acc[n] = __builtin_amdgcn_mfma_f32_16x16x32_f16(af, bf, acc[n], 0, 0, 0);
            }
        }
        // C/D layout (validated r1-r15): col = lane&15 (B-row), row = (lane>>4)*4+j (A-row)
#pragma unroll
        for (int n = 0; n < 7; ++n) {
            int col = n * 16 + r16;
            if (col < 100) {
#pragma unroll
                for (int j = 0; j < 4; ++j) {
                    int rr = wave * 16 + g4 * 4 + j;
                    if (rr < 100) simL[rr * 102 + col] = (_Float16)acc[n][j];
                }
            }
        }
    }
    __syncthreads();

    // ---- gaussian kernels + log pooling: thread = (h, cdd-row), psum[20] static ----
    if (tid < 500) {
        int h = tid / 100;           // 0..4
        int row = tid - h * 100;     // 0..99
        float psum[20];
#pragma unroll
        for (int k = 0; k < 20; ++k) psum[k] = 0.f;

        const _Float16* sp = simL + row * 102 + h * 20;
        const float* mp = mS + h * 20;
#pragma unroll 4
        for (int t = 0; t < 20; ++t) {
            float s  = (float)sp[t];
            float mm = mp[t];
            float a  = -50.0f * s * s;
#pragma unroll
            for (int k = 0; k < 19; ++k) {
                const float mu = -0.9f + 0.1f * (float)k;
                float arg = fmaf(100.0f * mu, s, a - 50.0f * mu * mu);   // -50(s-mu)^2
                psum[k] = fmaf(__expf(arg), mm, psum[k]);
            }
            float d = s - 1.0f;
            psum[19] = fmaf(__expf(-500000.0f * d * d), mm, psum[19]);
        }
        float val = 0.f;
        const float* wp = wS + h * 20;
#pragma unroll
        for (int k = 0; k < 20; ++k)
            val += __logf(fmaxf(psum[k], 1e-10f)) * wp[k];
        svals[tid] = val * 0.01f * cS[row];
    }
    __syncthreads();

    // ---- per-candidate partial for this chunk ----
    if (tid < 5) {
        float ssum = 0.f;
        for (int h = 0; h < 5; ++h)
#pragma unroll
            for (int r = 0; r < 20; ++r)
                ssum += svals[h * 100 + tid * 20 + r];
        partial[(b * 5 + tid) * NCHUNK + chunk] = ssum;
    }
}

// ---------------- Kernel 3: sum chunks + bias + log_softmax over C=5 --------------------
__global__ __launch_bounds__(64) void finalize(const float* __restrict__ partial,
                                               const float* __restrict__ ltr_b,
                                               float* __restrict__ out)
{
    int b = blockIdx.x;
    int tid = threadIdx.x;
    __shared__ float sc[5];
    if (tid < 5) {
        float a = ltr_b[0];
        const float* pp = partial + (b * 5 + tid) * NCHUNK;
#pragma unroll
        for (int ch = 0; ch < NCHUNK; ++ch) a += pp[ch];
        sc[tid] = a;
    }
    __syncthreads();
    if (tid < 5) {
        float m = fmaxf(fmaxf(fmaxf(sc[0], sc[1]), fmaxf(sc[2], sc[3])), sc[4]);
        float sum = 0.f;
#pragma unroll
        for (int i = 0; i < 5; ++i) sum += __expf(sc[i] - m);
        out[b * 5 + tid] = sc[tid] - m - __logf(sum);
    }
}

extern "C" void kernel_launch(void* const* d_in, const int* in_sizes, int n_in,
                              void* d_out, int out_size, void* d_ws, size_t ws_size,
                              hipStream_t stream)
{
    const int*   cand = (const int*)d_in[0];
    const int*   clk  = (const int*)d_in[1];
    const float* cpad = (const float*)d_in[2];
    const float* hpad = (const float*)d_in[3];
    const float* emb  = (const float*)d_in[4];
    const float* lw   = (const float*)d_in[5];
    const float* lb   = (const float*)d_in[6];
    float* out = (float*)d_out;

    _Float16* wsH  = (_Float16*)d_ws;                                   // 22.528 MB
    // partial lives past ws rows + 4 KB slack (stage overreads <2 KB past wsH end)
    float* partial = (float*)((char*)d_ws + (size_t)(NROW_CDD + NROW_HIS) * KP * 2 + 4096);

    hipLaunchKernelGGL(gather_norm, dim3((NROW_CDD + NROW_HIS) / 4), dim3(256), 0, stream,
                       cand, clk, emb, wsH);
    hipLaunchKernelGGL(knrm_fused, dim3(NCHUNK, B_), dim3(512), 0, stream,
                       wsH, cpad, hpad, lw, partial);
    hipLaunchKernelGGL(finalize, dim3(B_), dim3(64), 0, stream, partial, lb, out);
}

// Round 17
// 45.191 us; speedup vs baseline: 1.2075x; 1.1678x over previous
//
#include <hip/hip_runtime.h>
#include <hip/hip_fp16.h>

typedef _Float16 half8 __attribute__((ext_vector_type(8)));
typedef _Float16 half4v __attribute__((ext_vector_type(4)));
typedef float float4v __attribute__((ext_vector_type(4)));

#define E_DIM 300
#define KP 320               // padded K (10 MFMA k-steps of 32)
#define B_ 32
#define NROW_CDD 3200        // 32*5*20
#define NROW_HIS 32000       // 32*50*20

// ---------------- Kernel 1: gather + l2-normalize -> fp16 rows (K padded to 320) --------
__global__ __launch_bounds__(256) void gather_norm(const int* __restrict__ cand,
                                                   const int* __restrict__ clk,
                                                   const float* __restrict__ emb,
                                                   _Float16* __restrict__ outH)
{
    int row  = blockIdx.x * 4 + (threadIdx.x >> 6);
    int lane = threadIdx.x & 63;
    int tok = (row < NROW_CDD) ? cand[row] : clk[row - NROW_CDD];
    const float* e = emb + (long)tok * E_DIM;
    float v[5];
    float ss = 0.f;
#pragma unroll
    for (int j = 0; j < 5; ++j) {
        int idx = lane + j * 64;
        float x = (idx < E_DIM) ? e[idx] : 0.f;
        v[j] = x;
        ss += x * x;
    }
#pragma unroll
    for (int off = 32; off; off >>= 1) ss += __shfl_xor(ss, off);
    float scale = 1.0f / fmaxf(sqrtf(ss), 1e-12f);
    _Float16* o = outH + (long)row * KP;
#pragma unroll
    for (int j = 0; j < 5; ++j) {
        int idx = lane + j * 64;
        o[idx] = (_Float16)((idx < E_DIM) ? v[j] * scale : 0.f);
    }
}

// ---------------- Kernel 2: hybrid streaming GEMM: A in regs, B chunk in LDS ------------
// grid (16, 32) = 512 blocks, 448 threads (7 waves). Wave w owns A rows 16w..16w+15
// (af[10] hoisted in regs, R11-style streaming); block stages B 64-col chunk (41 KB LDS).
// LDS ~54 KB -> 2 blocks/CU, 2 rounds -> cross-block overlap. ~63 MB total traffic.
__global__ __launch_bounds__(448, 2) void sim_gemm(const _Float16* __restrict__ wsH,
                                                   _Float16* __restrict__ simW)
{
    __shared__ __align__(16) char Bbuf[64 * 640 + 128];   // 41 KB (+swizzle pad)
    __shared__ _Float16 simT[100 * 66];                   // 13.2 KB

    int b = blockIdx.y, ntile = blockIdx.x;               // cols ntile*64..+63
    int tid = threadIdx.x;
    int wave = tid >> 6, lane = tid & 63;
    int g4 = lane >> 4, r16 = lane & 15;

    const char* gA = (const char*)(wsH + (size_t)b * 100 * KP);
    const char* gB = (const char*)(wsH + (size_t)(NROW_CDD + b * 1000) * KP);

    // ---- hoist A slice: 10 independent global 16B loads (this wave's 16 rows) ----
    int rA = wave * 16 + r16; if (rA > 99) rA = 99;
    const char* pA = gA + (size_t)rA * 640;
    half8 af[10];
#pragma unroll
    for (int k = 0; k < 10; ++k) af[k] = *(const half8*)(pA + k * 64 + g4 * 16);

    // ---- stage B chunk: 64 rows x 640 B = 2560 uint4, two-phase hoisted ----
    uint4 bv[6];
#pragma unroll
    for (int j = 0; j < 6; ++j) {
        int u = tid + 448 * j; if (u > 2559) u = 2559;
        int r = u / 40;
        int gr = ntile * 64 + r; if (gr > 999) gr = 999;
        bv[j] = *(const uint4*)(gB + (size_t)(gr * 40 + (u - r * 40)) * 16);
    }
#pragma unroll
    for (int j = 0; j < 6; ++j) {
        int u = tid + 448 * j;
        if (u < 2560) {
            int r = u / 40;
            *(uint4*)(Bbuf + ((u * 16) ^ ((r & 7) << 4))) = bv[j];
        }
    }
    __syncthreads();

    // ---- k-loop: 4 ds_read_b128 + 4 MFMA per k ----
    float4v acc[4];
#pragma unroll
    for (int n = 0; n < 4; ++n) acc[n] = (float4v){0.f, 0.f, 0.f, 0.f};

#pragma unroll
    for (int k = 0; k < 10; ++k) {
#pragma unroll
        for (int n = 0; n < 4; ++n) {
            int rB = n * 16 + r16;
            half8 bf = *(const half8*)(Bbuf + ((rB * 640 + k * 64 + g4 * 16) ^ ((rB & 7) << 4)));
            acc[n] = __builtin_amdgcn_mfma_f32_16x16x32_f16(af[k], bf, acc[n], 0, 0, 0);
        }
    }

    // C/D layout (validated r1-r16): col = lane&15 (B-row), row = (lane>>4)*4+j (A-row)
#pragma unroll
    for (int n = 0; n < 4; ++n) {
#pragma unroll
        for (int j = 0; j < 4; ++j) {
            int r = wave * 16 + g4 * 4 + j;
            if (r < 100) simT[r * 66 + n * 16 + r16] = (_Float16)acc[n][j];
        }
    }
    __syncthreads();

    // ---- coalesced fp16 write-out: 100 rows x 64 cols ----
    size_t obase = (size_t)b * 100000 + (size_t)ntile * 64;
    for (int u = tid; u < 6400; u += 448) {
        int r = u >> 6, c = u & 63;
        int gcol = ntile * 64 + c;
        if (gcol < 1000) simW[(size_t)(b * 100 + r) * 1000 + ntile * 64 + c] = simT[r * 66 + c];
    }
    (void)obase;
}

// ---------------- Kernel 3: gaussian kernels + log pooling, one block per sim row -------
__global__ __launch_bounds__(256) void knrm_pool(const _Float16* __restrict__ simW,
                                                 const float* __restrict__ cpad,
                                                 const float* __restrict__ hpad,
                                                 const float* __restrict__ ltr_w,
                                                 float* __restrict__ rowsum)
{
    __shared__ float sS[50 * 21];
    __shared__ float mS[50 * 21];
    __shared__ float wS[1000];
    __shared__ float part[4];

    int row = blockIdx.x;            // (b*5+c)*20 + s
    int b = row / 100;
    int tid = threadIdx.x;

    if (tid < 250) {
        int p = tid * 4;
        half4v hv = *(const half4v*)(simW + (size_t)row * 1000 + p);
        float4v mv = *(const float4v*)(hpad + (size_t)b * 1000 + p);
        *(float4v*)&wS[p] = *(const float4v*)(ltr_w + p);
#pragma unroll
        for (int q = 0; q < 4; ++q) {
            int pq = p + q, h = pq / 20, t = pq - h * 20;
            sS[h * 21 + t] = (float)hv[q];
            mS[h * 21 + t] = mv[q];
        }
    }
    __syncthreads();

    float val = 0.f;
    if (tid < 250) {
        int h = tid % 50, kq = tid / 50;     // kq 0..4, k = kq*4+j
        float bj[4], cj[4];
        bool is19[4];
#pragma unroll
        for (int j = 0; j < 4; ++j) {
            float mu = -0.9f + 0.1f * (float)(kq * 4 + j);
            bj[j] = 100.0f * mu;
            cj[j] = -50.0f * mu * mu;
            is19[j] = (kq * 4 + j) == 19;
        }
        float psum0 = 0.f, psum1 = 0.f, psum2 = 0.f, psum3 = 0.f;
        const float* sp = sS + h * 21;
        const float* mp = mS + h * 21;
#pragma unroll 4
        for (int t = 0; t < 20; ++t) {
            float s  = sp[t];
            float mm = mp[t];
            float d  = s - 1.0f;
            float arg19 = -500000.0f * d * d;
            float a0 = is19[0] ? arg19 : fmaf(fmaf(-50.0f, s, bj[0]), s, cj[0]);
            float a1 = is19[1] ? arg19 : fmaf(fmaf(-50.0f, s, bj[1]), s, cj[1]);
            float a2 = is19[2] ? arg19 : fmaf(fmaf(-50.0f, s, bj[2]), s, cj[2]);
            float a3 = is19[3] ? arg19 : fmaf(fmaf(-50.0f, s, bj[3]), s, cj[3]);
            psum0 = fmaf(__expf(a0), mm, psum0);
            psum1 = fmaf(__expf(a1), mm, psum1);
            psum2 = fmaf(__expf(a2), mm, psum2);
            psum3 = fmaf(__expf(a3), mm, psum3);
        }
        const float* wp = wS + h * 20 + kq * 4;
        val  = __logf(fmaxf(psum0, 1e-10f)) * wp[0];
        val += __logf(fmaxf(psum1, 1e-10f)) * wp[1];
        val += __logf(fmaxf(psum2, 1e-10f)) * wp[2];
        val += __logf(fmaxf(psum3, 1e-10f)) * wp[3];
    }
#pragma unroll
    for (int off = 32; off; off >>= 1) val += __shfl_down(val, off);
    int wave = tid >> 6, lane = tid & 63;
    if (lane == 0) part[wave] = val;
    __syncthreads();
    if (tid == 0)
        rowsum[row] = (part[0] + part[1] + part[2] + part[3]) * 0.01f * cpad[row];
}

// ---------------- Kernel 4: sum rows per (b,c) + bias + log_softmax over C=5 ------------
__global__ __launch_bounds__(64) void finalize(const float* __restrict__ rowsum,
                                               const float* __restrict__ ltr_b,
                                               float* __restrict__ out)
{
    int b = blockIdx.x;
    int tid = threadIdx.x;
    __shared__ float sc[5];
    if (tid < 5) {
        float a = ltr_b[0];
        const float* rp = rowsum + (b * 5 + tid) * 20;
#pragma unroll
        for (int s = 0; s < 20; ++s) a += rp[s];
        sc[tid] = a;
    }
    __syncthreads();
    if (tid < 5) {
        float m = fmaxf(fmaxf(fmaxf(sc[0], sc[1]), fmaxf(sc[2], sc[3])), sc[4]);
        float sum = 0.f;
#pragma unroll
        for (int i = 0; i < 5; ++i) sum += __expf(sc[i] - m);
        out[b * 5 + tid] = sc[tid] - m - __logf(sum);
    }
}

extern "C" void kernel_launch(void* const* d_in, const int* in_sizes, int n_in,
                              void* d_out, int out_size, void* d_ws, size_t ws_size,
                              hipStream_t stream)
{
    const int*   cand = (const int*)d_in[0];
    const int*   clk  = (const int*)d_in[1];
    const float* cpad = (const float*)d_in[2];
    const float* hpad = (const float*)d_in[3];
    const float* emb  = (const float*)d_in[4];
    const float* lw   = (const float*)d_in[5];
    const float* lb   = (const float*)d_in[6];
    float* out = (float*)d_out;

    _Float16* wsH  = (_Float16*)d_ws;                                                   // 22.528 MB
    _Float16* simW = (_Float16*)((char*)d_ws + (size_t)(NROW_CDD + NROW_HIS) * KP * 2); // 6.4 MB
    float* rowsum  = (float*)((char*)simW + (size_t)B_ * 100 * 1000 * 2);               // 12.8 KB

    hipLaunchKernelGGL(gather_norm, dim3((NROW_CDD + NROW_HIS) / 4), dim3(256), 0, stream,
                       cand, clk, emb, wsH);
    hipLaunchKernelGGL(sim_gemm, dim3(16, B_), dim3(448), 0, stream, wsH, simW);
    hipLaunchKernelGGL(knrm_pool, dim3(NROW_CDD), dim3(256), 0, stream,
                       simW, cpad, hpad, lw, rowsum);
    hipLaunchKernelGGL(finalize, dim3(B_), dim3(64), 0, stream, rowsum, lb, out);
}